// Round 1
// baseline (28.112 us; speedup 1.0000x reference)
//
#include <hip/hip_runtime.h>
#include <hip/hip_bf16.h>

using bf16x8 = __attribute__((ext_vector_type(8))) short;
using f32x4  = __attribute__((ext_vector_type(4))) float;

static constexpr int kN     = 100000;
static constexpr int kFIN   = 128;
static constexpr int kHID   = 64;
static constexpr int kC     = 192;       // F_IN + HID (weight row count)
static constexpr int kTiles = kN / 16;   // 6250, exact

// round-to-nearest-even f32 -> bf16 (inputs are finite; no NaN handling)
__device__ __forceinline__ short f2bf(float v) {
    union { float f; unsigned u; } a; a.f = v;
    unsigned r = a.u + 0x7fffu + ((a.u >> 16) & 1u);
    return (short)(r >> 16);
}

// Pack W_sum = W[0,0,:128,:] + W[1,0,:128,:] into bf16 MFMA B-fragment order:
//   element (mat,k,c): kk=k>>5, g=(k>>3)&3, e=k&7, jt=c>>4, lane=g*16+(c&15)
//   dst short index = ((mat*4+kk)*4+jt)*512 + lane*8 + e        (32 KB total)
__global__ void prep_weights(const float* __restrict__ Wz,
                             const float* __restrict__ Wh,
                             short* __restrict__ wpack) {
    int idx = blockIdx.x * blockDim.x + threadIdx.x;   // 0..16383
    if (idx >= 2 * kFIN * kHID) return;
    int mat = idx >> 13;
    int rem = idx & 8191;
    int k = rem >> 6;
    int c = rem & 63;
    const float* W = mat ? Wh : Wz;
    float v = W[k * kHID + c] + W[kC * kHID + k * kHID + c];
    int kk = k >> 5, g = (k >> 3) & 3, e = k & 7;
    int jt = c >> 4, lane = g * 16 + (c & 15);
    wpack[((mat * 4 + kk) * 4 + jt) * 512 + lane * 8 + e] = f2bf(v);
}

__global__ __launch_bounds__(256) void fused_gcn(
    const float* __restrict__ x,
    const short* __restrict__ wpack,
    const float* __restrict__ bz,
    const float* __restrict__ bh,
    const float* __restrict__ wlin,
    const float* __restrict__ blin,
    float* __restrict__ out)
{
    __shared__ short lw[16384];   // 32 KB packed weights
    {
        const int4* src = (const int4*)wpack;
        int4* dst = (int4*)lw;
        int t = threadIdx.x;
        #pragma unroll
        for (int i = 0; i < 8; ++i) dst[t + 256 * i] = src[t + 256 * i];
    }
    __syncthreads();

    const int t    = threadIdx.x;
    const int wid  = t >> 6;
    const int lane = t & 63;
    const int tile = blockIdx.x * 4 + wid;
    if (tile >= kTiles) return;
    const int r = lane & 15;      // A-fragment row within tile / C-fragment col
    const int g = lane >> 4;      // k-group
    const int node0 = tile * 16;

    // ---- A loads: X[node0+r][kk*32 + g*8 .. +7], all 8 dwordx4 in flight ----
    const float* xrow = x + (size_t)(node0 + r) * kFIN;
    f32x4 f[8];
    #pragma unroll
    for (int kk = 0; kk < 4; ++kk) {
        int k0 = kk * 32 + g * 8;
        f[kk * 2]     = *(const f32x4*)(xrow + k0);
        f[kk * 2 + 1] = *(const f32x4*)(xrow + k0 + 4);
    }
    bf16x8 a[4];
    #pragma unroll
    for (int kk = 0; kk < 4; ++kk) {
        #pragma unroll
        for (int e = 0; e < 4; ++e) {
            a[kk][e]     = f2bf(f[kk * 2][e]);
            a[kk][e + 4] = f2bf(f[kk * 2 + 1][e]);
        }
    }

    // ---- MFMA: two [16x128]x[128x64] tiles (z and h pre-activations) ----
    f32x4 accz[4], acch[4];
    #pragma unroll
    for (int jt = 0; jt < 4; ++jt) {
        accz[jt] = f32x4{0.f, 0.f, 0.f, 0.f};
        acch[jt] = f32x4{0.f, 0.f, 0.f, 0.f};
    }
    #pragma unroll
    for (int kk = 0; kk < 4; ++kk) {
        #pragma unroll
        for (int jt = 0; jt < 4; ++jt) {
            bf16x8 wz = *(const bf16x8*)&lw[((0 * 4 + kk) * 4 + jt) * 512 + lane * 8];
            bf16x8 wh = *(const bf16x8*)&lw[((1 * 4 + kk) * 4 + jt) * 512 + lane * 8];
            accz[jt] = __builtin_amdgcn_mfma_f32_16x16x32_bf16(a[kk], wz, accz[jt], 0, 0, 0);
            acch[jt] = __builtin_amdgcn_mfma_f32_16x16x32_bf16(a[kk], wh, acch[jt], 0, 0, 0);
        }
    }

    // ---- epilogue: sigmoid/tanh/GRU/relu, dot with Wlin, 16-lane reduce ----
    // C layout: channel = jt*16 + r, node-in-tile = g*4 + reg
    float contrib[4] = {0.f, 0.f, 0.f, 0.f};
    #pragma unroll
    for (int jt = 0; jt < 4; ++jt) {
        int c = jt * 16 + r;
        float bzc = bz[c], bhc = bh[c], wlc = wlin[c];
        #pragma unroll
        for (int i = 0; i < 4; ++i) {
            float z  = 1.0f / (1.0f + __expf(-(accz[jt][i] + bzc)));
            float ht = tanhf(acch[jt][i] + bhc);
            float H  = (1.0f - z) * ht;
            contrib[i] += (H > 0.f ? H : 0.f) * wlc;
        }
    }
    #pragma unroll
    for (int m = 1; m < 16; m <<= 1) {
        #pragma unroll
        for (int i = 0; i < 4; ++i)
            contrib[i] += __shfl_xor(contrib[i], m, 64);
    }
    if (r == 0) {
        float bl = blin[0];
        #pragma unroll
        for (int i = 0; i < 4; ++i)
            out[node0 + g * 4 + i] = contrib[i] + bl;
    }
}

extern "C" void kernel_launch(void* const* d_in, const int* in_sizes, int n_in,
                              void* d_out, int out_size, void* d_ws, size_t ws_size,
                              hipStream_t stream) {
    const float* x    = (const float*)d_in[0];
    // d_in[1] edge_index, d_in[2] edge_weight: dead code in reference (K=1, H0=0)
    const float* Wz   = (const float*)d_in[3];
    const float* bz   = (const float*)d_in[4];
    // d_in[5] Wr, d_in[6] br: dead (R*H0 == 0)
    const float* Wh   = (const float*)d_in[7];
    const float* bh   = (const float*)d_in[8];
    const float* wlin = (const float*)d_in[9];
    const float* blin = (const float*)d_in[10];
    short* wpack = (short*)d_ws;   // 32 KB of scratch used

    prep_weights<<<dim3(64), dim3(256), 0, stream>>>(Wz, Wh, wpack);
    const int nblk = (kTiles + 3) / 4;   // 1563
    fused_gcn<<<dim3(nblk), dim3(256), 0, stream>>>(
        x, wpack, bz, bh, wlin, blin, (float*)d_out);
}

// Round 2
// 23.994 us; speedup vs baseline: 1.1716x; 1.1716x over previous
//
#include <hip/hip_runtime.h>
#include <hip/hip_bf16.h>

using bf16x8 = __attribute__((ext_vector_type(8))) short;
using f32x4  = __attribute__((ext_vector_type(4))) float;

static constexpr int kN     = 100000;
static constexpr int kFIN   = 128;
static constexpr int kHID   = 64;
static constexpr int kC     = 192;       // F_IN + HID (weight row count)
static constexpr int kTiles = kN / 16;   // 6250, exact

// round-to-nearest-even f32 -> bf16 (inputs are finite; no NaN handling)
__device__ __forceinline__ short f2bf(float v) {
    union { float f; unsigned u; } a; a.f = v;
    unsigned r = a.u + 0x7fffu + ((a.u >> 16) & 1u);
    return (short)(r >> 16);
}

// Fast activations: v_exp_f32 / v_rcp_f32 (~1e-7 rel err, << bf16 noise).
// Saturation behavior is exact at +/-inf arguments of exp.
__device__ __forceinline__ float rcp_fast(float x) { return __builtin_amdgcn_rcpf(x); }
__device__ __forceinline__ float sigmoid_fast(float x) {
    return rcp_fast(1.0f + __expf(-x));
}
__device__ __forceinline__ float tanh_fast(float x) {
    float e = __expf(2.0f * x);          // overflow->inf->rcp->0 => tanh=1
    return 1.0f - 2.0f * rcp_fast(e + 1.0f);
}

// Pack W_sum = W[0,0,:128,:] + W[1,0,:128,:] into bf16 MFMA B-fragment order:
//   element (mat,k,c): kk=k>>5, g=(k>>3)&3, e=k&7, jt=c>>4, lane=g*16+(c&15)
//   dst short index = ((mat*4+kk)*4+jt)*512 + lane*8 + e        (32 KB total)
__global__ void prep_weights(const float* __restrict__ Wz,
                             const float* __restrict__ Wh,
                             short* __restrict__ wpack) {
    int idx = blockIdx.x * blockDim.x + threadIdx.x;   // 0..16383
    if (idx >= 2 * kFIN * kHID) return;
    int mat = idx >> 13;
    int rem = idx & 8191;
    int k = rem >> 6;
    int c = rem & 63;
    const float* W = mat ? Wh : Wz;
    float v = W[k * kHID + c] + W[kC * kHID + k * kHID + c];
    int kk = k >> 5, g = (k >> 3) & 3, e = k & 7;
    int jt = c >> 4, lane = g * 16 + (c & 15);
    wpack[((mat * 4 + kk) * 4 + jt) * 512 + lane * 8 + e] = f2bf(v);
}

__global__ __launch_bounds__(256) void fused_gcn(
    const float* __restrict__ x,
    const short* __restrict__ wpack,
    const float* __restrict__ bz,
    const float* __restrict__ bh,
    const float* __restrict__ wlin,
    const float* __restrict__ blin,
    float* __restrict__ out)
{
    __shared__ short lw[16384];   // 32 KB packed weights
    {
        const int4* src = (const int4*)wpack;
        int4* dst = (int4*)lw;
        int tt = threadIdx.x;
        #pragma unroll
        for (int i = 0; i < 8; ++i) dst[tt + 256 * i] = src[tt + 256 * i];
    }
    __syncthreads();

    const int t    = threadIdx.x;
    const int wid  = t >> 6;
    const int lane = t & 63;
    const int r = lane & 15;      // A-fragment row within tile / C-fragment col
    const int g = lane >> 4;      // k-group
    const int base = blockIdx.x * 8 + wid * 2;   // 2 tiles per wave

    // Hoisted per-lane epilogue constants (same for both tiles)
    float bzc[4], bhc[4], wlc[4];
    #pragma unroll
    for (int jt = 0; jt < 4; ++jt) {
        int c = jt * 16 + r;
        bzc[jt] = bz[c]; bhc[jt] = bh[c]; wlc[jt] = wlin[c];
    }
    const float bl = blin[0];

    auto load_x = [&](f32x4* f, int tile) {
        const float* xrow = x + (size_t)(tile * 16 + r) * kFIN;
        #pragma unroll
        for (int kk = 0; kk < 4; ++kk) {
            int k0 = kk * 32 + g * 8;
            f[kk * 2]     = *(const f32x4*)(xrow + k0);
            f[kk * 2 + 1] = *(const f32x4*)(xrow + k0 + 4);
        }
    };

    auto compute_tile = [&](const f32x4* f, int tile) {
        bf16x8 a[4];
        #pragma unroll
        for (int kk = 0; kk < 4; ++kk) {
            #pragma unroll
            for (int e = 0; e < 4; ++e) {
                a[kk][e]     = f2bf(f[kk * 2][e]);
                a[kk][e + 4] = f2bf(f[kk * 2 + 1][e]);
            }
        }
        f32x4 accz[4], acch[4];
        #pragma unroll
        for (int jt = 0; jt < 4; ++jt) {
            accz[jt] = f32x4{0.f, 0.f, 0.f, 0.f};
            acch[jt] = f32x4{0.f, 0.f, 0.f, 0.f};
        }
        #pragma unroll
        for (int kk = 0; kk < 4; ++kk) {
            #pragma unroll
            for (int jt = 0; jt < 4; ++jt) {
                bf16x8 wz = *(const bf16x8*)&lw[((0 * 4 + kk) * 4 + jt) * 512 + lane * 8];
                bf16x8 wh = *(const bf16x8*)&lw[((1 * 4 + kk) * 4 + jt) * 512 + lane * 8];
                accz[jt] = __builtin_amdgcn_mfma_f32_16x16x32_bf16(a[kk], wz, accz[jt], 0, 0, 0);
                acch[jt] = __builtin_amdgcn_mfma_f32_16x16x32_bf16(a[kk], wh, acch[jt], 0, 0, 0);
            }
        }
        // epilogue: C layout channel = jt*16 + r, node-in-tile = g*4 + reg
        float contrib[4] = {0.f, 0.f, 0.f, 0.f};
        #pragma unroll
        for (int jt = 0; jt < 4; ++jt) {
            #pragma unroll
            for (int i = 0; i < 4; ++i) {
                float z  = sigmoid_fast(accz[jt][i] + bzc[jt]);
                float ht = tanh_fast(acch[jt][i] + bhc[jt]);
                float H  = (1.0f - z) * ht;
                contrib[i] += (H > 0.f ? H : 0.f) * wlc[jt];
            }
        }
        #pragma unroll
        for (int m = 1; m < 16; m <<= 1) {
            #pragma unroll
            for (int i = 0; i < 4; ++i)
                contrib[i] += __shfl_xor(contrib[i], m, 64);
        }
        if (r == 0) {
            #pragma unroll
            for (int i = 0; i < 4; ++i)
                out[tile * 16 + g * 4 + i] = contrib[i] + bl;
        }
    };

    const int tile0 = base, tile1 = base + 1;
    f32x4 f0[8], f1[8];
    if (tile0 < kTiles) load_x(f0, tile0);   // both load batches in flight
    if (tile1 < kTiles) load_x(f1, tile1);   // before any compute
    if (tile0 < kTiles) compute_tile(f0, tile0);
    if (tile1 < kTiles) compute_tile(f1, tile1);
}

extern "C" void kernel_launch(void* const* d_in, const int* in_sizes, int n_in,
                              void* d_out, int out_size, void* d_ws, size_t ws_size,
                              hipStream_t stream) {
    const float* x    = (const float*)d_in[0];
    // d_in[1] edge_index, d_in[2] edge_weight: dead code in reference (K=1, H0=0)
    const float* Wz   = (const float*)d_in[3];
    const float* bz   = (const float*)d_in[4];
    // d_in[5] Wr, d_in[6] br: dead (R*H0 == 0)
    const float* Wh   = (const float*)d_in[7];
    const float* bh   = (const float*)d_in[8];
    const float* wlin = (const float*)d_in[9];
    const float* blin = (const float*)d_in[10];
    short* wpack = (short*)d_ws;   // 32 KB of scratch used

    prep_weights<<<dim3(64), dim3(256), 0, stream>>>(Wz, Wh, wpack);
    const int nblk = (kTiles + 7) / 8;   // 782 blocks, 8 tiles each
    fused_gcn<<<dim3(nblk), dim3(256), 0, stream>>>(
        x, wpack, bz, bh, wlin, blin, (float*)d_out);
}

// Round 3
// 19.440 us; speedup vs baseline: 1.4461x; 1.2343x over previous
//
#include <hip/hip_runtime.h>
#include <hip/hip_bf16.h>

using bf16x8 = __attribute__((ext_vector_type(8))) short;
using f32x4  = __attribute__((ext_vector_type(4))) float;

static constexpr int kN          = 100000;
static constexpr int kFIN        = 128;
static constexpr int kTermStride = 192 * 64;     // W term stride in floats
static constexpr int kTiles      = kN / 16;      // 6250, exact
static constexpr int kBlocks     = 768;          // 3 per CU exactly
static constexpr int kWaves      = kBlocks * 4;  // 3072
static constexpr int kBaseTiles  = kWaves * 2;   // 6144
static constexpr int kExtra      = kTiles - kBaseTiles;  // 106

// round-to-nearest-even f32 -> bf16 (inputs are finite; no NaN handling)
__device__ __forceinline__ short f2bf(float v) {
    union { float f; unsigned u; } a; a.f = v;
    unsigned r = a.u + 0x7fffu + ((a.u >> 16) & 1u);
    return (short)(r >> 16);
}

// Fast activations: v_exp_f32 / v_rcp_f32 (~1e-7 rel err, << bf16 noise).
__device__ __forceinline__ float rcp_fast(float x) { return __builtin_amdgcn_rcpf(x); }
__device__ __forceinline__ float sigmoid_fast(float x) {
    return rcp_fast(1.0f + __expf(-x));
}
__device__ __forceinline__ float tanh_fast(float x) {
    float e = __expf(2.0f * x);          // overflow->inf->rcp->0 => tanh=1
    return 1.0f - 2.0f * rcp_fast(e + 1.0f);
}

// Single fused kernel. Each block packs W_sum = W[0,0,:128,:]+W[1,0,:128,:]
// (z and h mats) into bf16 MFMA B-fragment order in LDS, then processes
// 16-node tiles: x -> bf16 -> two [16x128]x[128x64] MFMAs -> GRU epilogue
// -> dot with Wlin -> out.  Pack layout, element (mat,k,c):
//   kk=k>>5, g=(k>>3)&3, e=k&7, jt=c>>4, ln=g*16+(c&15)
//   short idx = ((mat*4+kk)*4+jt)*512 + ln*8 + e     (32 KB total)
__global__ __launch_bounds__(256, 4) void fused_gcn(
    const float* __restrict__ x,
    const float* __restrict__ Wz,
    const float* __restrict__ bz,
    const float* __restrict__ Wh,
    const float* __restrict__ bh,
    const float* __restrict__ wlin,
    const float* __restrict__ blin,
    float* __restrict__ out)
{
    __shared__ short lw[16384];   // 32 KB packed weights

    const int t    = threadIdx.x;
    const int wid  = t >> 6;
    const int lane = t & 63;
    const int r    = lane & 15;   // A row within tile / C channel low bits
    const int g    = lane >> 4;   // k-group
    const int gw   = blockIdx.x * 4 + wid;
    const int t0   = gw * 2, t1 = t0 + 1;
    const int t2   = (gw < kExtra) ? kBaseTiles + gw : -1;

    f32x4 f[8];
    auto load_x = [&](int tile) {
        const float* xrow = x + (size_t)(tile * 16 + r) * kFIN;
        #pragma unroll
        for (int kk = 0; kk < 4; ++kk) {
            f[kk * 2]     = *(const f32x4*)(xrow + kk * 32 + g * 8);
            f[kk * 2 + 1] = *(const f32x4*)(xrow + kk * 32 + g * 8 + 4);
        }
    };

    load_x(t0);   // first tile's HBM loads in flight during the weight pack

    // ---- pack weights into LDS (coalesced L2-hit loads, scalar b16 stores)
    #pragma unroll
    for (int mat = 0; mat < 2; ++mat) {
        const float* W = mat ? Wh : Wz;
        #pragma unroll
        for (int it = 0; it < 8; ++it) {
            int fidx = it * 1024 + t * 4;
            f32x4 w0 = *(const f32x4*)(W + fidx);
            f32x4 w1 = *(const f32x4*)(W + kTermStride + fidx);
            #pragma unroll
            for (int i = 0; i < 4; ++i) {
                int fi = fidx + i;
                int k = fi >> 6, c = fi & 63;
                int kk = k >> 5, gg = (k >> 3) & 3, e = k & 7;
                int jt = c >> 4, ln = gg * 16 + (c & 15);
                lw[((mat * 4 + kk) * 4 + jt) * 512 + ln * 8 + e] = f2bf(w0[i] + w1[i]);
            }
        }
    }
    __syncthreads();

    // Hoisted per-lane epilogue constants
    float bzc[4], bhc[4], wlc[4];
    #pragma unroll
    for (int jt = 0; jt < 4; ++jt) {
        int c = jt * 16 + r;
        bzc[jt] = bz[c]; bhc[jt] = bh[c]; wlc[jt] = wlin[c];
    }
    const float bl = blin[0];

    bf16x8 a[4];
    auto cvt = [&]() {
        #pragma unroll
        for (int kk = 0; kk < 4; ++kk) {
            #pragma unroll
            for (int e = 0; e < 4; ++e) {
                a[kk][e]     = f2bf(f[kk * 2][e]);
                a[kk][e + 4] = f2bf(f[kk * 2 + 1][e]);
            }
        }
    };

    auto compute_tile = [&](int tile) {
        f32x4 accz[4], acch[4];
        #pragma unroll
        for (int jt = 0; jt < 4; ++jt) {
            accz[jt] = f32x4{0.f, 0.f, 0.f, 0.f};
            acch[jt] = f32x4{0.f, 0.f, 0.f, 0.f};
        }
        #pragma unroll
        for (int kk = 0; kk < 4; ++kk) {
            #pragma unroll
            for (int jt = 0; jt < 4; ++jt) {
                bf16x8 wz = *(const bf16x8*)&lw[((0 * 4 + kk) * 4 + jt) * 512 + lane * 8];
                bf16x8 wh = *(const bf16x8*)&lw[((1 * 4 + kk) * 4 + jt) * 512 + lane * 8];
                accz[jt] = __builtin_amdgcn_mfma_f32_16x16x32_bf16(a[kk], wz, accz[jt], 0, 0, 0);
                acch[jt] = __builtin_amdgcn_mfma_f32_16x16x32_bf16(a[kk], wh, acch[jt], 0, 0, 0);
            }
        }
        // epilogue: C layout channel = jt*16 + r, node-in-tile = g*4 + reg
        float contrib[4] = {0.f, 0.f, 0.f, 0.f};
        #pragma unroll
        for (int jt = 0; jt < 4; ++jt) {
            #pragma unroll
            for (int i = 0; i < 4; ++i) {
                float z  = sigmoid_fast(accz[jt][i] + bzc[jt]);
                float ht = tanh_fast(acch[jt][i] + bhc[jt]);
                float H  = (1.0f - z) * ht;
                contrib[i] += (H > 0.f ? H : 0.f) * wlc[jt];
            }
        }
        #pragma unroll
        for (int m = 1; m < 16; m <<= 1) {
            #pragma unroll
            for (int i = 0; i < 4; ++i)
                contrib[i] += __shfl_xor(contrib[i], m, 64);
        }
        if (r == 0) {
            #pragma unroll
            for (int i = 0; i < 4; ++i)
                out[tile * 16 + g * 4 + i] = contrib[i] + bl;
        }
    };

    // tile 0
    cvt();
    load_x(t1);          // prefetch next while computing
    compute_tile(t0);
    // tile 1
    cvt();
    if (t2 >= 0) load_x(t2);
    compute_tile(t1);
    // optional tile 2 (first 106 waves)
    if (t2 >= 0) {
        cvt();
        compute_tile(t2);
    }
}

extern "C" void kernel_launch(void* const* d_in, const int* in_sizes, int n_in,
                              void* d_out, int out_size, void* d_ws, size_t ws_size,
                              hipStream_t stream) {
    const float* x    = (const float*)d_in[0];
    // d_in[1] edge_index, d_in[2] edge_weight: dead code in reference (K=1, H0=0)
    const float* Wz   = (const float*)d_in[3];
    const float* bz   = (const float*)d_in[4];
    // d_in[5] Wr, d_in[6] br: dead (R*H0 == 0)
    const float* Wh   = (const float*)d_in[7];
    const float* bh   = (const float*)d_in[8];
    const float* wlin = (const float*)d_in[9];
    const float* blin = (const float*)d_in[10];

    fused_gcn<<<dim3(kBlocks), dim3(256), 0, stream>>>(
        x, Wz, bz, Wh, bh, wlin, blin, (float*)d_out);
}